// Round 3
// baseline (237.788 us; speedup 1.0000x reference)
//
#include <hip/hip_runtime.h>

#define DEVI __device__ __forceinline__

typedef short short4_t __attribute__((ext_vector_type(4)));
typedef short short8_t __attribute__((ext_vector_type(8)));
typedef __bf16 bf16x8 __attribute__((ext_vector_type(8)));
typedef float f32x4 __attribute__((ext_vector_type(4)));

// float -> bf16 bits, round-to-nearest-even
DEVI short f2bf(float f) {
    union { float f; unsigned u; } v; v.f = f;
    unsigned r = (v.u + 0x7fffu + ((v.u >> 16) & 1u)) >> 16;
    return (short)r;
}

// pack two floats to packed bf16 (round-half-up): one add each + one v_perm
DEVI unsigned pack_ru(float a, float b) {
    union { float f; unsigned u; } x, y; x.f = a; y.f = b;
    return __builtin_amdgcn_perm(y.u + 0x8000u, x.u + 0x8000u, 0x07060302u);
}

// async global->LDS, 16B per lane; lds dest must be wave-uniform base (+lane*16 implicit)
DEVI void g2lds16(const short* g, short* l) {
    __builtin_amdgcn_global_load_lds(
        (const __attribute__((address_space(1))) void*)g,
        (__attribute__((address_space(3))) void*)l, 16, 0, 0);
}

// ---------------- convert q,k,v fp32 -> bf16 concatenated [12288,1024] ----------------
__global__ __launch_bounds__(256) void cvt3_kernel(const float* __restrict__ q,
                                                   const float* __restrict__ k,
                                                   const float* __restrict__ v,
                                                   short* __restrict__ X) {
    const size_t N1 = (size_t)4096 * 1024;
    size_t e = ((size_t)blockIdx.x * 256 + threadIdx.x) * 4;
    const float* src; size_t off;
    if (e < N1)            { src = q; off = e; }
    else if (e < 2 * N1)   { src = k; off = e - N1; }
    else                   { src = v; off = e - 2 * N1; }
    f32x4 f = *(const f32x4*)(src + off);
    short4_t o;
    o[0] = f2bf(f[0]); o[1] = f2bf(f[1]); o[2] = f2bf(f[2]); o[3] = f2bf(f[3]);
    *(short4_t*)(X + e) = o;
}

// ---------------- W [1024][1024] fp32 row-major [k][n] -> Wt bf16 [n][k] ----------------
__global__ __launch_bounds__(256) void transpose_w_kernel(const float* __restrict__ W,
                                                          short* __restrict__ Wt) {
    __shared__ short T[64][65];
    const int t = threadIdx.x;
    const int kt = blockIdx.x * 64, nt = blockIdx.y * 64;
#pragma unroll
    for (int r = 0; r < 4; ++r) {
        int kl = (t >> 4) + 16 * r;
        int n0 = (t & 15) * 4;
        f32x4 f = *(const f32x4*)(W + (size_t)(kt + kl) * 1024 + nt + n0);
#pragma unroll
        for (int j = 0; j < 4; ++j) T[n0 + j][kl] = f2bf(f[j]);
    }
    __syncthreads();
#pragma unroll
    for (int r = 0; r < 2; ++r) {
        int nl = (t >> 3) + 32 * r;
        int k0 = (t & 7) * 8;
        short8_t v;
#pragma unroll
        for (int j = 0; j < 8; ++j) v[j] = T[nl][k0 + j];
        *(short8_t*)(Wt + (size_t)(nt + nl) * 1024 + kt + k0) = v;
    }
}

// ---------------- GEMM 128x128  C[M][N] = A[M][K]*Bt[N][K]^T + bias ----------------
template <typename OutT>
__global__ __launch_bounds__(256) void gemm_bt_kernel(const short* __restrict__ A,
                                                      const short* __restrict__ Bt,
                                                      const float* __restrict__ bias,
                                                      OutT* __restrict__ C,
                                                      int M, int N, int K,
                                                      int qrows, float qscale) {
    __shared__ __align__(16) short As[128 * 32];
    __shared__ __align__(16) short Bs[128 * 32];
    const int tid  = threadIdx.x;
    const int lane = tid & 63, wave = tid >> 6;
    const int quad = lane >> 4, l16 = lane & 15;
    const int row0 = blockIdx.x * 128, col0 = blockIdx.y * 128;
    const int wm = (wave >> 1) * 64, wn = (wave & 1) * 64;
    const int srow = lane >> 2;
    const int scol = (lane & 3) * 8;
    f32x4 acc[4][4] = {};
    for (int k0 = 0; k0 < K; k0 += 32) {
#pragma unroll
        for (int r = 0; r < 2; ++r) {
            int rb = r * 64 + wave * 16;
            g2lds16(A  + (size_t)(row0 + rb + srow) * K + k0 + scol, &As[rb * 32]);
            g2lds16(Bt + (size_t)(col0 + rb + srow) * K + k0 + scol, &Bs[rb * 32]);
        }
        __syncthreads();
        bf16x8 af[4], bfr[4];
#pragma unroll
        for (int mi = 0; mi < 4; ++mi) af[mi]  = *(const bf16x8*)&As[(wm + mi * 16 + l16) * 32 + quad * 8];
#pragma unroll
        for (int ni = 0; ni < 4; ++ni) bfr[ni] = *(const bf16x8*)&Bs[(wn + ni * 16 + l16) * 32 + quad * 8];
#pragma unroll
        for (int mi = 0; mi < 4; ++mi)
#pragma unroll
            for (int ni = 0; ni < 4; ++ni)
                acc[mi][ni] = __builtin_amdgcn_mfma_f32_16x16x32_bf16(af[mi], bfr[ni], acc[mi][ni], 0, 0, 0);
        __syncthreads();
    }
#pragma unroll
    for (int mi = 0; mi < 4; ++mi) {
#pragma unroll
        for (int ni = 0; ni < 4; ++ni) {
            int col = col0 + wn + ni * 16 + l16;
            float bv = bias[col];
#pragma unroll
            for (int i = 0; i < 4; ++i) {
                int row = row0 + wm + mi * 16 + quad * 4 + i;
                float val = acc[mi][ni][i] + bv;
                if (row < qrows) val *= qscale;
                if constexpr (sizeof(OutT) == 2) C[(size_t)row * N + col] = (OutT)f2bf(val);
                else                             C[(size_t)row * N + col] = (OutT)val;
            }
        }
    }
}

// ---------------- GEMM 64x128 tiles (more blocks/CU for the small output GEMM) ----------------
__global__ __launch_bounds__(256) void gemm_bt64_kernel(const short* __restrict__ A,
                                                        const short* __restrict__ Bt,
                                                        const float* __restrict__ bias,
                                                        float* __restrict__ C,
                                                        int M, int N, int K) {
    __shared__ __align__(16) short As[64 * 32];
    __shared__ __align__(16) short Bs[128 * 32];
    const int tid  = threadIdx.x;
    const int lane = tid & 63, wave = tid >> 6;
    const int quad = lane >> 4, l16 = lane & 15;
    const int row0 = blockIdx.x * 64, col0 = blockIdx.y * 128;
    const int wn = wave * 32;
    const int srow = lane >> 2;
    const int scol = (lane & 3) * 8;
    f32x4 acc[4][2] = {};
    for (int k0 = 0; k0 < K; k0 += 32) {
        {
            int rb = wave * 16;
            g2lds16(A + (size_t)(row0 + rb + srow) * K + k0 + scol, &As[rb * 32]);
        }
#pragma unroll
        for (int r = 0; r < 2; ++r) {
            int rb = r * 64 + wave * 16;
            g2lds16(Bt + (size_t)(col0 + rb + srow) * K + k0 + scol, &Bs[rb * 32]);
        }
        __syncthreads();
        bf16x8 af[4], bfr[2];
#pragma unroll
        for (int mi = 0; mi < 4; ++mi) af[mi]  = *(const bf16x8*)&As[(mi * 16 + l16) * 32 + quad * 8];
#pragma unroll
        for (int ni = 0; ni < 2; ++ni) bfr[ni] = *(const bf16x8*)&Bs[(wn + ni * 16 + l16) * 32 + quad * 8];
#pragma unroll
        for (int mi = 0; mi < 4; ++mi)
#pragma unroll
            for (int ni = 0; ni < 2; ++ni)
                acc[mi][ni] = __builtin_amdgcn_mfma_f32_16x16x32_bf16(af[mi], bfr[ni], acc[mi][ni], 0, 0, 0);
        __syncthreads();
    }
#pragma unroll
    for (int mi = 0; mi < 4; ++mi) {
#pragma unroll
        for (int ni = 0; ni < 2; ++ni) {
            int col = col0 + wn + ni * 16 + l16;
            float bv = bias[col];
#pragma unroll
            for (int i = 0; i < 4; ++i) {
                int row = row0 + mi * 16 + quad * 4 + i;
                C[(size_t)row * N + col] = acc[mi][ni][i] + bv;
            }
        }
    }
}

// ---------------- P_v [b*2048+s][1024] head slice -> VT[(h*2+b)*64+d][2048] ----------------
__global__ __launch_bounds__(256) void transpose_v_kernel(const short* __restrict__ Pv,
                                                          short* __restrict__ VT) {
    __shared__ short T[64][65];
    const int t = threadIdx.x;
    const int hb = blockIdx.x, st = blockIdx.y * 64;
    const int h = hb >> 1, b = hb & 1;
#pragma unroll
    for (int r = 0; r < 2; ++r) {
        int sl = (t >> 3) + 32 * r;
        short8_t v = *(const short8_t*)(Pv + (size_t)(b * 2048 + st + sl) * 1024 + h * 64 + (t & 7) * 8);
#pragma unroll
        for (int j = 0; j < 8; ++j) T[(t & 7) * 8 + j][sl] = v[j];
    }
    __syncthreads();
#pragma unroll
    for (int r = 0; r < 2; ++r) {
        int dl = (t >> 3) + 32 * r;
        short8_t v;
#pragma unroll
        for (int j = 0; j < 8; ++j) v[j] = T[dl][(t & 7) * 8 + j];
        *(short8_t*)(VT + ((size_t)hb * 64 + dl) * 2048 + st + (t & 7) * 8) = v;
    }
}

// ---------------- flash attention v10: kv-split, miq=4 ----------------
// v9 + kv-split: waves 0-1 handle kv 0..1023, waves 2-3 handle kv 1024..2047; each wave owns
// 64 q rows (miq=4). Each K/V LDS fragment read now feeds 4 MFMAs (vs 2) -> compute-loop
// ds_read_b128 per block halves (2048 -> 1024) at identical MFMA count. Each sub-block
// single-buffers its K/V tile (same total LDS, 2 blocks/CU preserved); 8 tiles x 2 barriers
// = 16 barriers (same as v9). Register prefetch still overlaps compute. kv-half partials
// (O^T f32 + rowsums) are combined via an LDS exchange in the epilogue.
__global__ __launch_bounds__(256, 2) void attn_kernel(const short* __restrict__ P,
                                                      const short* __restrict__ VT,
                                                      short* __restrict__ O) {
    constexpr int LDK = 72;   // 144B rows: b128 frag reads conflict-free
    constexpr int LDV = 136;  // 272B rows: b128 frag reads conflict-free
    constexpr int LDO = 72;   // epilogue transpose stride
    constexpr int LDF = 68;   // f32 exchange stride (272B rows)
    union SmemU {
        struct { short Ks[2][128 * LDK]; short Vs[2][64 * LDV]; } s;     // [sub-block]
        struct { float Of[2][64 * LDF]; float Osum[2][64]; short OT[128 * LDO]; } r;
    };
    __shared__ __align__(16) SmemU sm;

    const int t = threadIdx.x;
    const int lane = t & 63, wave = t >> 6;
    const int quad = lane >> 4, l16 = lane & 15;
    // XCD swizzle: 512 blocks, xcd = bx&7 -> each XCD owns 4 hb (K/V slices fit its L2)
    const int bx = blockIdx.x;
    const int xcd = bx & 7, bi = bx >> 3;
    const int hb = xcd * 4 + (bi & 3), qt = bi >> 2;   // hb 0..31, qt 0..15 (128-row q tiles)
    const int h = hb >> 1, b = hb & 1;
    const short* Pq  = P + (size_t)(b * 2048 + qt * 128) * 1024 + h * 64;
    const short* Pk  = P + (size_t)(4096 + b * 2048) * 1024 + h * 64;
    const short* VTh = VT + (size_t)hb * 64 * 2048;

    const int sb = wave >> 1;          // kv half: 0 -> kv 0..1023, 1 -> kv 1024..2047
    const int wq = (wave & 1) * 64;    // q rows of this wave (64 rows, miq=4)
    const int ts = t & 127;            // thread id within sub-block (128 threads)

    // Q fragments: registers for the whole KV loop (B-operand layout = Q rows)
    bf16x8 qf[4][2];
#pragma unroll
    for (int miq = 0; miq < 4; ++miq)
#pragma unroll
        for (int kh = 0; kh < 2; ++kh)
            qf[miq][kh] = *(const bf16x8*)(Pq + (size_t)(wq + miq * 16 + l16) * 1024 + kh * 32 + quad * 8);

    // ones A-operand for the row-sum MFMA
    bf16x8 ones;
#pragma unroll
    for (int j = 0; j < 8; ++j) ones[j] = (__bf16)1.0f;

    f32x4 oacc[4][4] = {};   // [di][miq], O^T C-layout: d=quad*4+i, q=l16
    f32x4 osum[4] = {};      // row-sum accumulator (this kv half)

    // K staging: 16 rows/pass x 8 per sub-block; LDS row permuted within each 32-row group
    const int krow16 = ts >> 3, kc8 = (ts & 7) * 8;
    // V staging: 8 rows/pass x 8 (d-rows, kv-contiguous, unpermuted)
    const int vrow8 = ts >> 4, vc8 = (ts & 15) * 8;

    const size_t kvbase = (size_t)sb * 1024;
    short8_t kreg[8], vreg[8];
#pragma unroll
    for (int it = 0; it < 8; ++it) {
        kreg[it] = *(const short8_t*)(Pk + (kvbase + it * 16 + krow16) * 1024 + kc8);
        vreg[it] = *(const short8_t*)(VTh + (size_t)(it * 8 + vrow8) * 2048 + kvbase + vc8);
    }

    short* Ksb = sm.s.Ks[sb];
    short* Vsb = sm.s.Vs[sb];

    for (int tile = 0; tile < 8; ++tile) {
#pragma unroll
        for (int it = 0; it < 8; ++it) {
            // permuted LDS row within the 32-row group (same mapping as v7/v9)
            int w32 = ((it & 1) << 4) + krow16;
            int kj = w32 & 7, kq = w32 >> 3;
            int lr = (it >> 1) * 32 + (kj >= 4 ? 16 + (kj - 4) : kj) + kq * 4;
            *(short8_t*)&Ksb[lr * LDK + kc8] = kreg[it];
            *(short8_t*)&Vsb[(it * 8 + vrow8) * LDV + vc8] = vreg[it];
        }
        __syncthreads();   // tile data visible (also fences prior tile's reads vs these writes)
        if (tile + 1 < 8) {   // global prefetch overlaps the whole compute phase
            size_t kv0 = kvbase + (size_t)(tile + 1) * 128;
#pragma unroll
            for (int it = 0; it < 8; ++it) {
                kreg[it] = *(const short8_t*)(Pk + (kv0 + it * 16 + krow16) * 1024 + kc8);
                vreg[it] = *(const short8_t*)(VTh + (size_t)(it * 8 + vrow8) * 2048 + kv0 + vc8);
            }
        }
#pragma unroll
        for (int p = 0; p < 4; ++p) {   // 4 pairs of 16-row chunks = 128 kv
            // K A-frags: chunkA rows p*32+l16, chunkB rows p*32+16+l16 (permuted kv space)
            bf16x8 aA0 = *(const bf16x8*)&Ksb[(p * 32 + l16) * LDK + quad * 8];
            bf16x8 aA1 = *(const bf16x8*)&Ksb[(p * 32 + l16) * LDK + 32 + quad * 8];
            bf16x8 aB0 = *(const bf16x8*)&Ksb[(p * 32 + 16 + l16) * LDK + quad * 8];
            bf16x8 aB1 = *(const bf16x8*)&Ksb[(p * 32 + 16 + l16) * LDK + 32 + quad * 8];
            // V A-frags for K=32 PV: lane d=l16, k(kv)=quad*8+j -> contiguous b128
            bf16x8 vA[4];
#pragma unroll
            for (int di = 0; di < 4; ++di)
                vA[di] = *(const bf16x8*)&Vsb[(di * 16 + l16) * LDV + p * 32 + quad * 8];
#pragma unroll
            for (int miq = 0; miq < 4; ++miq) {
                f32x4 sA = {}, sB = {};
                sA = __builtin_amdgcn_mfma_f32_16x16x32_bf16(aA0, qf[miq][0], sA, 0, 0, 0);
                sB = __builtin_amdgcn_mfma_f32_16x16x32_bf16(aB0, qf[miq][0], sB, 0, 0, 0);
                sA = __builtin_amdgcn_mfma_f32_16x16x32_bf16(aA1, qf[miq][1], sA, 0, 0, 0);
                sB = __builtin_amdgcn_mfma_f32_16x16x32_bf16(aB1, qf[miq][1], sB, 0, 0, 0);
                // exp2 (scale folded into Q); lane's 8 values = kv quad*8+{0..7} of this pair
                float eA0 = __builtin_amdgcn_exp2f(sA[0]);
                float eA1 = __builtin_amdgcn_exp2f(sA[1]);
                float eA2 = __builtin_amdgcn_exp2f(sA[2]);
                float eA3 = __builtin_amdgcn_exp2f(sA[3]);
                float eB0 = __builtin_amdgcn_exp2f(sB[0]);
                float eB1 = __builtin_amdgcn_exp2f(sB[1]);
                float eB2 = __builtin_amdgcn_exp2f(sB[2]);
                float eB3 = __builtin_amdgcn_exp2f(sB[3]);
                union { unsigned u[4]; bf16x8 b8; } pb;
                pb.u[0] = pack_ru(eA0, eA1);
                pb.u[1] = pack_ru(eA2, eA3);
                pb.u[2] = pack_ru(eB0, eB1);
                pb.u[3] = pack_ru(eB2, eB3);
                // row sums via MFMA: D[r][q] = sum_kv pb[kv][q], identical across r
                osum[miq] = __builtin_amdgcn_mfma_f32_16x16x32_bf16(ones, pb.b8, osum[miq], 0, 0, 0);
                // O^T += V^T * P at K=32 (full rate)
#pragma unroll
                for (int di = 0; di < 4; ++di)
                    oacc[di][miq] = __builtin_amdgcn_mfma_f32_16x16x32_bf16(vA[di], pb.b8, oacc[di][miq], 0, 0, 0);
            }
        }
        __syncthreads();   // all reads of this tile done before next overwrite
    }

    // ---- combine kv halves: sub-block 1 dumps partials, sub-block 0 reduces ----
    const int wv = wave & 1;
    if (sb == 1) {
#pragma unroll
        for (int di = 0; di < 4; ++di)
#pragma unroll
            for (int miq = 0; miq < 4; ++miq)
                *(f32x4*)&sm.r.Of[wv][(miq * 16 + l16) * LDF + di * 16 + quad * 4] = oacc[di][miq];
        if (quad == 0) {
#pragma unroll
            for (int miq = 0; miq < 4; ++miq)
                sm.r.Osum[wv][miq * 16 + l16] = osum[miq][0];
        }
    }
    __syncthreads();
    if (sb == 0) {
        float rinv[4];
#pragma unroll
        for (int miq = 0; miq < 4; ++miq)
            rinv[miq] = 1.0f / (osum[miq][0] + sm.r.Osum[wv][miq * 16 + l16]);
#pragma unroll
        for (int di = 0; di < 4; ++di) {
#pragma unroll
            for (int miq = 0; miq < 4; ++miq) {
                f32x4 ob = *(const f32x4*)&sm.r.Of[wv][(miq * 16 + l16) * LDF + di * 16 + quad * 4];
                float v0 = (oacc[di][miq][0] + ob[0]) * rinv[miq];
                float v1 = (oacc[di][miq][1] + ob[1]) * rinv[miq];
                float v2 = (oacc[di][miq][2] + ob[2]) * rinv[miq];
                float v3 = (oacc[di][miq][3] + ob[3]) * rinv[miq];
                uint2 w;
                w.x = pack_ru(v0, v1);
                w.y = pack_ru(v2, v3);
                int q = wq + miq * 16 + l16;
                *(uint2*)&sm.r.OT[q * LDO + di * 16 + quad * 4] = w;
            }
        }
    }
    __syncthreads();
    {
        const int orow = t >> 1, ocol = (t & 1) * 32;
        short* dst = O + (size_t)(b * 2048 + qt * 128 + orow) * 1024 + h * 64 + ocol;
#pragma unroll
        for (int c = 0; c < 4; ++c)
            *(short8_t*)(dst + c * 8) = *(const short8_t*)&sm.r.OT[orow * LDO + ocol + c * 8];
    }
}

extern "C" void kernel_launch(void* const* d_in, const int* in_sizes, int n_in,
                              void* d_out, int out_size, void* d_ws, size_t ws_size,
                              hipStream_t stream) {
    (void)in_sizes; (void)n_in; (void)out_size; (void)ws_size;
    const float* q  = (const float*)d_in[0];
    const float* k  = (const float*)d_in[1];
    const float* v  = (const float*)d_in[2];
    const float* Wq = (const float*)d_in[3];
    const float* bq = (const float*)d_in[4];
    const float* Wo = (const float*)d_in[5];
    const float* bo = (const float*)d_in[6];
    float* out = (float*)d_out;

    short* Xcat = (short*)d_ws;                        // [12288][1024] bf16
    short* WqT  = Xcat + (size_t)12288 * 1024;         // [1024][1024]
    short* WoT  = WqT + (size_t)1024 * 1024;           // [1024][1024]
    short* P    = WoT + (size_t)1024 * 1024;           // [12288][1024] (q|k|v projections)
    short* VT   = P + (size_t)12288 * 1024;            // [32][64][2048]
    short* O    = VT + (size_t)32 * 64 * 2048;         // [4096][1024]

    // softmax scale * log2(e), folded into Q rows of the projection GEMM
    const float qscale = 0.022097086912079608f * 1.4426950408889634f;

    cvt3_kernel<<<12288, 256, 0, stream>>>(q, k, v, Xcat);
    transpose_w_kernel<<<dim3(16, 16), 256, 0, stream>>>(Wq, WqT);
    transpose_w_kernel<<<dim3(16, 16), 256, 0, stream>>>(Wo, WoT);
    gemm_bt_kernel<short><<<dim3(96, 8), 256, 0, stream>>>(Xcat, WqT, bq, P, 12288, 1024, 1024, 4096, qscale);
    transpose_v_kernel<<<dim3(32, 32), 256, 0, stream>>>(P + (size_t)8192 * 1024, VT);
    attn_kernel<<<512, 256, 0, stream>>>(P, VT, O);
    gemm_bt64_kernel<<<dim3(64, 8), 256, 0, stream>>>(O, WoT, bo, out, 4096, 1024, 1024);
}

// Round 4
// 237.439 us; speedup vs baseline: 1.0015x; 1.0015x over previous
//
#include <hip/hip_runtime.h>

#define DEVI __device__ __forceinline__

typedef short short4_t __attribute__((ext_vector_type(4)));
typedef short short8_t __attribute__((ext_vector_type(8)));
typedef __bf16 bf16x8 __attribute__((ext_vector_type(8)));
typedef float f32x4 __attribute__((ext_vector_type(4)));

// float -> bf16 bits, round-to-nearest-even
DEVI short f2bf(float f) {
    union { float f; unsigned u; } v; v.f = f;
    unsigned r = (v.u + 0x7fffu + ((v.u >> 16) & 1u)) >> 16;
    return (short)r;
}

// pack two floats to packed bf16 (round-half-up): one add each + one v_perm
DEVI unsigned pack_ru(float a, float b) {
    union { float f; unsigned u; } x, y; x.f = a; y.f = b;
    return __builtin_amdgcn_perm(y.u + 0x8000u, x.u + 0x8000u, 0x07060302u);
}

// async global->LDS, 16B per lane; lds dest must be wave-uniform base (+lane*16 implicit)
DEVI void g2lds16(const short* g, short* l) {
    __builtin_amdgcn_global_load_lds(
        (const __attribute__((address_space(1))) void*)g,
        (__attribute__((address_space(3))) void*)l, 16, 0, 0);
}

// ---------------- convert q,k,v fp32 -> bf16 concatenated [12288,1024] ----------------
__global__ __launch_bounds__(256) void cvt3_kernel(const float* __restrict__ q,
                                                   const float* __restrict__ k,
                                                   const float* __restrict__ v,
                                                   short* __restrict__ X) {
    const size_t N1 = (size_t)4096 * 1024;
    size_t e = ((size_t)blockIdx.x * 256 + threadIdx.x) * 4;
    const float* src; size_t off;
    if (e < N1)            { src = q; off = e; }
    else if (e < 2 * N1)   { src = k; off = e - N1; }
    else                   { src = v; off = e - 2 * N1; }
    f32x4 f = *(const f32x4*)(src + off);
    short4_t o;
    o[0] = f2bf(f[0]); o[1] = f2bf(f[1]); o[2] = f2bf(f[2]); o[3] = f2bf(f[3]);
    *(short4_t*)(X + e) = o;
}

// ---------------- W [1024][1024] fp32 row-major [k][n] -> Wt bf16 [n][k] ----------------
__global__ __launch_bounds__(256) void transpose_w_kernel(const float* __restrict__ W,
                                                          short* __restrict__ Wt) {
    __shared__ short T[64][65];
    const int t = threadIdx.x;
    const int kt = blockIdx.x * 64, nt = blockIdx.y * 64;
#pragma unroll
    for (int r = 0; r < 4; ++r) {
        int kl = (t >> 4) + 16 * r;
        int n0 = (t & 15) * 4;
        f32x4 f = *(const f32x4*)(W + (size_t)(kt + kl) * 1024 + nt + n0);
#pragma unroll
        for (int j = 0; j < 4; ++j) T[n0 + j][kl] = f2bf(f[j]);
    }
    __syncthreads();
#pragma unroll
    for (int r = 0; r < 2; ++r) {
        int nl = (t >> 3) + 32 * r;
        int k0 = (t & 7) * 8;
        short8_t v;
#pragma unroll
        for (int j = 0; j < 8; ++j) v[j] = T[nl][k0 + j];
        *(short8_t*)(Wt + (size_t)(nt + nl) * 1024 + kt + k0) = v;
    }
}

// ---------------- GEMM 128x128  C[M][N] = A[M][K]*Bt[N][K]^T + bias ----------------
template <typename OutT>
__global__ __launch_bounds__(256) void gemm_bt_kernel(const short* __restrict__ A,
                                                      const short* __restrict__ Bt,
                                                      const float* __restrict__ bias,
                                                      OutT* __restrict__ C,
                                                      int M, int N, int K,
                                                      int qrows, float qscale) {
    __shared__ __align__(16) short As[128 * 32];
    __shared__ __align__(16) short Bs[128 * 32];
    const int tid  = threadIdx.x;
    const int lane = tid & 63, wave = tid >> 6;
    const int quad = lane >> 4, l16 = lane & 15;
    const int row0 = blockIdx.x * 128, col0 = blockIdx.y * 128;
    const int wm = (wave >> 1) * 64, wn = (wave & 1) * 64;
    const int srow = lane >> 2;
    const int scol = (lane & 3) * 8;
    f32x4 acc[4][4] = {};
    for (int k0 = 0; k0 < K; k0 += 32) {
#pragma unroll
        for (int r = 0; r < 2; ++r) {
            int rb = r * 64 + wave * 16;
            g2lds16(A  + (size_t)(row0 + rb + srow) * K + k0 + scol, &As[rb * 32]);
            g2lds16(Bt + (size_t)(col0 + rb + srow) * K + k0 + scol, &Bs[rb * 32]);
        }
        __syncthreads();
        bf16x8 af[4], bfr[4];
#pragma unroll
        for (int mi = 0; mi < 4; ++mi) af[mi]  = *(const bf16x8*)&As[(wm + mi * 16 + l16) * 32 + quad * 8];
#pragma unroll
        for (int ni = 0; ni < 4; ++ni) bfr[ni] = *(const bf16x8*)&Bs[(wn + ni * 16 + l16) * 32 + quad * 8];
#pragma unroll
        for (int mi = 0; mi < 4; ++mi)
#pragma unroll
            for (int ni = 0; ni < 4; ++ni)
                acc[mi][ni] = __builtin_amdgcn_mfma_f32_16x16x32_bf16(af[mi], bfr[ni], acc[mi][ni], 0, 0, 0);
        __syncthreads();
    }
#pragma unroll
    for (int mi = 0; mi < 4; ++mi) {
#pragma unroll
        for (int ni = 0; ni < 4; ++ni) {
            int col = col0 + wn + ni * 16 + l16;
            float bv = bias[col];
#pragma unroll
            for (int i = 0; i < 4; ++i) {
                int row = row0 + wm + mi * 16 + quad * 4 + i;
                float val = acc[mi][ni][i] + bv;
                if (row < qrows) val *= qscale;
                if constexpr (sizeof(OutT) == 2) C[(size_t)row * N + col] = (OutT)f2bf(val);
                else                             C[(size_t)row * N + col] = (OutT)val;
            }
        }
    }
}

// ---------------- GEMM 64x128 tiles (more blocks/CU for the small output GEMM) ----------------
__global__ __launch_bounds__(256) void gemm_bt64_kernel(const short* __restrict__ A,
                                                        const short* __restrict__ Bt,
                                                        const float* __restrict__ bias,
                                                        float* __restrict__ C,
                                                        int M, int N, int K) {
    __shared__ __align__(16) short As[64 * 32];
    __shared__ __align__(16) short Bs[128 * 32];
    const int tid  = threadIdx.x;
    const int lane = tid & 63, wave = tid >> 6;
    const int quad = lane >> 4, l16 = lane & 15;
    const int row0 = blockIdx.x * 64, col0 = blockIdx.y * 128;
    const int wn = wave * 32;
    const int srow = lane >> 2;
    const int scol = (lane & 3) * 8;
    f32x4 acc[4][2] = {};
    for (int k0 = 0; k0 < K; k0 += 32) {
        {
            int rb = wave * 16;
            g2lds16(A + (size_t)(row0 + rb + srow) * K + k0 + scol, &As[rb * 32]);
        }
#pragma unroll
        for (int r = 0; r < 2; ++r) {
            int rb = r * 64 + wave * 16;
            g2lds16(Bt + (size_t)(col0 + rb + srow) * K + k0 + scol, &Bs[rb * 32]);
        }
        __syncthreads();
        bf16x8 af[4], bfr[2];
#pragma unroll
        for (int mi = 0; mi < 4; ++mi) af[mi]  = *(const bf16x8*)&As[(mi * 16 + l16) * 32 + quad * 8];
#pragma unroll
        for (int ni = 0; ni < 2; ++ni) bfr[ni] = *(const bf16x8*)&Bs[(wn + ni * 16 + l16) * 32 + quad * 8];
#pragma unroll
        for (int mi = 0; mi < 4; ++mi)
#pragma unroll
            for (int ni = 0; ni < 2; ++ni)
                acc[mi][ni] = __builtin_amdgcn_mfma_f32_16x16x32_bf16(af[mi], bfr[ni], acc[mi][ni], 0, 0, 0);
        __syncthreads();
    }
#pragma unroll
    for (int mi = 0; mi < 4; ++mi) {
#pragma unroll
        for (int ni = 0; ni < 2; ++ni) {
            int col = col0 + wn + ni * 16 + l16;
            float bv = bias[col];
#pragma unroll
            for (int i = 0; i < 4; ++i) {
                int row = row0 + mi * 16 + quad * 4 + i;
                C[(size_t)row * N + col] = acc[mi][ni][i] + bv;
            }
        }
    }
}

// ---------------- P_v [b*2048+s][1024] head slice -> VT[(h*2+b)*64+d][2048] ----------------
__global__ __launch_bounds__(256) void transpose_v_kernel(const short* __restrict__ Pv,
                                                          short* __restrict__ VT) {
    __shared__ short T[64][65];
    const int t = threadIdx.x;
    const int hb = blockIdx.x, st = blockIdx.y * 64;
    const int h = hb >> 1, b = hb & 1;
#pragma unroll
    for (int r = 0; r < 2; ++r) {
        int sl = (t >> 3) + 32 * r;
        short8_t v = *(const short8_t*)(Pv + (size_t)(b * 2048 + st + sl) * 1024 + h * 64 + (t & 7) * 8);
#pragma unroll
        for (int j = 0; j < 8; ++j) T[(t & 7) * 8 + j][sl] = v[j];
    }
    __syncthreads();
#pragma unroll
    for (int r = 0; r < 2; ++r) {
        int dl = (t >> 3) + 32 * r;
        short8_t v;
#pragma unroll
        for (int j = 0; j < 8; ++j) v[j] = T[dl][(t & 7) * 8 + j];
        *(short8_t*)(VT + ((size_t)hb * 64 + dl) * 2048 + st + (t & 7) * 8) = v;
    }
}

// ---------------- flash attention v11: v9 + V direct-from-L2 (no V LDS staging) ----------------
// v10 post-mortem: kv-split spilled ~43 MB of scratch (WRITE_SIZE 8->52 MB) -> reverted.
// v11 keeps v9's structure (miq=2, K staged+permuted in LDS, 1 barrier/tile, ones-MFMA row
// sums) and removes V's LDS staging: V fragments are read directly from global VT (L2-
// resident; each XCD serves 4 hb slices = 2 MB working set) with a ping-pong register
// prefetch one p-step ahead. vA[2][4] (32 VGPRs) replaces vreg[4] (32 VGPRs): net-zero
// registers, -1024 ds_read_b128 and -256 ds_write_b128 per block, LDS 71680 -> 36864 B.
__global__ __launch_bounds__(256, 2) void attn_kernel(const short* __restrict__ P,
                                                      const short* __restrict__ VT,
                                                      short* __restrict__ O) {
    constexpr int LDK = 72;   // 144B rows: b128 frag reads conflict-free
    constexpr int LDO = 72;   // epilogue transpose stride
    union SmemU {
        short Ks[2][128 * LDK];
        short OT[128 * LDO];
    };
    __shared__ __align__(16) SmemU sm;

    const int t = threadIdx.x;
    const int lane = t & 63, wave = t >> 6;
    const int quad = lane >> 4, l16 = lane & 15;
    // XCD swizzle: 512 blocks, xcd = bx&7 -> each XCD owns 4 hb (K/V slices fit its L2)
    const int bx = blockIdx.x;
    const int xcd = bx & 7, bi = bx >> 3;
    const int hb = xcd * 4 + (bi & 3), qt = bi >> 2;   // hb 0..31, qt 0..15 (128-row q tiles)
    const int h = hb >> 1, b = hb & 1;
    const short* Pq  = P + (size_t)(b * 2048 + qt * 128) * 1024 + h * 64;
    const short* Pk  = P + (size_t)(4096 + b * 2048) * 1024 + h * 64;
    const short* VTh = VT + (size_t)hb * 64 * 2048;
    const int wq = wave * 32;   // 32 q rows per wave

    // Q fragments: registers for the whole KV loop (B-operand layout = Q rows)
    bf16x8 qf[2][2];
#pragma unroll
    for (int miq = 0; miq < 2; ++miq)
#pragma unroll
        for (int kh = 0; kh < 2; ++kh)
            qf[miq][kh] = *(const bf16x8*)(Pq + (size_t)(wq + miq * 16 + l16) * 1024 + kh * 32 + quad * 8);

    // ones A-operand for the row-sum MFMA
    bf16x8 ones;
#pragma unroll
    for (int j = 0; j < 8; ++j) ones[j] = (__bf16)1.0f;

    f32x4 oacc[4][2] = {};   // [di][miq], O^T C-layout: d=quad*4+i, q=l16
    f32x4 osum[2] = {};      // row-sum accumulator

    // K staging: 32 rows/pass x 4; LDS row permuted within the 32-row group
    const int krow = t >> 3, kc8 = (t & 7) * 8;
    const int kj = krow & 7, kq = krow >> 3;
    const int lrow32 = (kj >= 4 ? 16 + (kj - 4) : kj) + kq * 4;   // permuted row within group

    short8_t kreg[4];
#pragma unroll
    for (int it = 0; it < 4; ++it)
        kreg[it] = *(const short8_t*)(Pk + (size_t)(it * 32 + krow) * 1024 + kc8);

    // V fragment base: lane covers row l16 (+di*16), 16B at col quad*8 (+kv offset)
    const short* Vg = VTh + (size_t)l16 * 2048 + quad * 8;
    // ping-pong V fragment registers, prefetched one p-step ahead
    bf16x8 vA[2][4];
#pragma unroll
    for (int di = 0; di < 4; ++di)
        vA[0][di] = *(const bf16x8*)(Vg + (size_t)di * 16 * 2048);   // tile0, p0

    for (int tile = 0; tile < 16; ++tile) {
        const int buf = tile & 1;
        short* Ksb = sm.Ks[buf];
#pragma unroll
        for (int it = 0; it < 4; ++it)
            *(short8_t*)&Ksb[(it * 32 + lrow32) * LDK + kc8] = kreg[it];
        __syncthreads();   // tile's K visible; also fences prior tile's reads (double-buffered)
        if (tile + 1 < 16) {   // K global prefetch overlaps the whole compute phase
            int kv0 = (tile + 1) * 128;
#pragma unroll
            for (int it = 0; it < 4; ++it)
                kreg[it] = *(const short8_t*)(Pk + (size_t)(kv0 + it * 32 + krow) * 1024 + kc8);
        }
#pragma unroll
        for (int p = 0; p < 4; ++p) {   // 4 pairs of 16-row chunks = 128 kv
            const int pp = p & 1;
            // prefetch next p-step's V frags (wraps to tile 0 at the very end; discarded)
            {
                const int ntile = (p == 3) ? ((tile + 1) & 15) : tile;
                const int np = (p + 1) & 3;
                const int ncol = ntile * 128 + np * 32;
#pragma unroll
                for (int di = 0; di < 4; ++di)
                    vA[pp ^ 1][di] = *(const bf16x8*)(Vg + (size_t)di * 16 * 2048 + ncol);
            }
            // K A-frags: chunkA rows p*32+l16, chunkB rows p*32+16+l16 (permuted kv space)
            bf16x8 aA0 = *(const bf16x8*)&Ksb[(p * 32 + l16) * LDK + quad * 8];
            bf16x8 aA1 = *(const bf16x8*)&Ksb[(p * 32 + l16) * LDK + 32 + quad * 8];
            bf16x8 aB0 = *(const bf16x8*)&Ksb[(p * 32 + 16 + l16) * LDK + quad * 8];
            bf16x8 aB1 = *(const bf16x8*)&Ksb[(p * 32 + 16 + l16) * LDK + 32 + quad * 8];
#pragma unroll
            for (int miq = 0; miq < 2; ++miq) {
                f32x4 sA = {}, sB = {};
                sA = __builtin_amdgcn_mfma_f32_16x16x32_bf16(aA0, qf[miq][0], sA, 0, 0, 0);
                sB = __builtin_amdgcn_mfma_f32_16x16x32_bf16(aB0, qf[miq][0], sB, 0, 0, 0);
                sA = __builtin_amdgcn_mfma_f32_16x16x32_bf16(aA1, qf[miq][1], sA, 0, 0, 0);
                sB = __builtin_amdgcn_mfma_f32_16x16x32_bf16(aB1, qf[miq][1], sB, 0, 0, 0);
                // exp2 (scale folded into Q); lane's 8 values = kv quad*8+{0..7} of this pair
                float eA0 = __builtin_amdgcn_exp2f(sA[0]);
                float eA1 = __builtin_amdgcn_exp2f(sA[1]);
                float eA2 = __builtin_amdgcn_exp2f(sA[2]);
                float eA3 = __builtin_amdgcn_exp2f(sA[3]);
                float eB0 = __builtin_amdgcn_exp2f(sB[0]);
                float eB1 = __builtin_amdgcn_exp2f(sB[1]);
                float eB2 = __builtin_amdgcn_exp2f(sB[2]);
                float eB3 = __builtin_amdgcn_exp2f(sB[3]);
                union { unsigned u[4]; bf16x8 b8; } pb;
                pb.u[0] = pack_ru(eA0, eA1);
                pb.u[1] = pack_ru(eA2, eA3);
                pb.u[2] = pack_ru(eB0, eB1);
                pb.u[3] = pack_ru(eB2, eB3);
                // row sums via MFMA: D[r][q] = sum_kv pb[kv][q], identical across r
                osum[miq] = __builtin_amdgcn_mfma_f32_16x16x32_bf16(ones, pb.b8, osum[miq], 0, 0, 0);
                // O^T += V^T * P at K=32 (full rate)
#pragma unroll
                for (int di = 0; di < 4; ++di)
                    oacc[di][miq] = __builtin_amdgcn_mfma_f32_16x16x32_bf16(vA[pp][di], pb.b8, oacc[di][miq], 0, 0, 0);
            }
        }
        // no end-of-tile barrier: double-buffered Ks + top-of-loop barrier make it redundant
    }

    // full row sums came from the ones-MFMA; aligned with O^T cols (q=l16) by construction
    float rinv[2];
#pragma unroll
    for (int miq = 0; miq < 2; ++miq) rinv[miq] = 1.0f / osum[miq][0];

    __syncthreads();   // all Ks reads done -> OT may alias them

    // O^T -> LDS (bf16), then coalesced row-major store
#pragma unroll
    for (int di = 0; di < 4; ++di) {
#pragma unroll
        for (int miq = 0; miq < 2; ++miq) {
            float v0 = oacc[di][miq][0] * rinv[miq];
            float v1 = oacc[di][miq][1] * rinv[miq];
            float v2 = oacc[di][miq][2] * rinv[miq];
            float v3 = oacc[di][miq][3] * rinv[miq];
            uint2 w;
            w.x = pack_ru(v0, v1);
            w.y = pack_ru(v2, v3);
            int q = wq + miq * 16 + l16;
            *(uint2*)&sm.OT[q * LDO + di * 16 + quad * 4] = w;
        }
    }
    __syncthreads();
    {
        const int orow = t >> 1, ocol = (t & 1) * 32;
        short* dst = O + (size_t)(b * 2048 + qt * 128 + orow) * 1024 + h * 64 + ocol;
#pragma unroll
        for (int c = 0; c < 4; ++c)
            *(short8_t*)(dst + c * 8) = *(const short8_t*)&sm.OT[orow * LDO + ocol + c * 8];
    }
}

extern "C" void kernel_launch(void* const* d_in, const int* in_sizes, int n_in,
                              void* d_out, int out_size, void* d_ws, size_t ws_size,
                              hipStream_t stream) {
    (void)in_sizes; (void)n_in; (void)out_size; (void)ws_size;
    const float* q  = (const float*)d_in[0];
    const float* k  = (const float*)d_in[1];
    const float* v  = (const float*)d_in[2];
    const float* Wq = (const float*)d_in[3];
    const float* bq = (const float*)d_in[4];
    const float* Wo = (const float*)d_in[5];
    const float* bo = (const float*)d_in[6];
    float* out = (float*)d_out;

    short* Xcat = (short*)d_ws;                        // [12288][1024] bf16
    short* WqT  = Xcat + (size_t)12288 * 1024;         // [1024][1024]
    short* WoT  = WqT + (size_t)1024 * 1024;           // [1024][1024]
    short* P    = WoT + (size_t)1024 * 1024;           // [12288][1024] (q|k|v projections)
    short* VT   = P + (size_t)12288 * 1024;            // [32][64][2048]
    short* O    = VT + (size_t)32 * 64 * 2048;         // [4096][1024]

    // softmax scale * log2(e), folded into Q rows of the projection GEMM
    const float qscale = 0.022097086912079608f * 1.4426950408889634f;

    cvt3_kernel<<<12288, 256, 0, stream>>>(q, k, v, Xcat);
    transpose_w_kernel<<<dim3(16, 16), 256, 0, stream>>>(Wq, WqT);
    transpose_w_kernel<<<dim3(16, 16), 256, 0, stream>>>(Wo, WoT);
    gemm_bt_kernel<short><<<dim3(96, 8), 256, 0, stream>>>(Xcat, WqT, bq, P, 12288, 1024, 1024, 4096, qscale);
    transpose_v_kernel<<<dim3(32, 32), 256, 0, stream>>>(P + (size_t)8192 * 1024, VT);
    attn_kernel<<<512, 256, 0, stream>>>(P, VT, O);
    gemm_bt64_kernel<<<dim3(64, 8), 256, 0, stream>>>(O, WoT, bo, out, 4096, 1024, 1024);
}

// Round 5
// 205.641 us; speedup vs baseline: 1.1563x; 1.1546x over previous
//
#include <hip/hip_runtime.h>

#define DEVI __device__ __forceinline__

typedef short short4_t __attribute__((ext_vector_type(4)));
typedef short short8_t __attribute__((ext_vector_type(8)));
typedef __bf16 bf16x8 __attribute__((ext_vector_type(8)));
typedef float f32x4 __attribute__((ext_vector_type(4)));

// float -> bf16 bits, round-to-nearest-even
DEVI short f2bf(float f) {
    union { float f; unsigned u; } v; v.f = f;
    unsigned r = (v.u + 0x7fffu + ((v.u >> 16) & 1u)) >> 16;
    return (short)r;
}

// pack two floats to packed bf16 (round-half-up): one add each + one v_perm
DEVI unsigned pack_ru(float a, float b) {
    union { float f; unsigned u; } x, y; x.f = a; y.f = b;
    return __builtin_amdgcn_perm(y.u + 0x8000u, x.u + 0x8000u, 0x07060302u);
}

// async global->LDS, 16B per lane; lds dest must be wave-uniform base (+lane*16 implicit)
DEVI void g2lds16(const short* g, short* l) {
    __builtin_amdgcn_global_load_lds(
        (const __attribute__((address_space(1))) void*)g,
        (__attribute__((address_space(3))) void*)l, 16, 0, 0);
}

// ---------------- fused prep: cvt q,k,v -> bf16 X[12288,1024]  AND  transpose Wq,Wo ----------------
// blocks 0..12287: convert; blocks 12288..12543: Wq^T; blocks 12544..12799: Wo^T
__global__ __launch_bounds__(256) void prep_kernel(const float* __restrict__ q,
                                                   const float* __restrict__ k,
                                                   const float* __restrict__ v,
                                                   short* __restrict__ X,
                                                   const float* __restrict__ Wq,
                                                   short* __restrict__ WqT,
                                                   const float* __restrict__ Wo,
                                                   short* __restrict__ WoT) {
    __shared__ short T[64][65];
    const int bx = blockIdx.x;
    const int t = threadIdx.x;
    if (bx < 12288) {
        const size_t N1 = (size_t)4096 * 1024;
        size_t e = ((size_t)bx * 256 + t) * 4;
        const float* src; size_t off;
        if (e < N1)            { src = q; off = e; }
        else if (e < 2 * N1)   { src = k; off = e - N1; }
        else                   { src = v; off = e - 2 * N1; }
        f32x4 f = *(const f32x4*)(src + off);
        short4_t o;
        o[0] = f2bf(f[0]); o[1] = f2bf(f[1]); o[2] = f2bf(f[2]); o[3] = f2bf(f[3]);
        *(short4_t*)(X + e) = o;
        return;
    }
    const int which = bx - 12288;               // 0..511
    const float* W = (which < 256) ? Wq : Wo;
    short* Wt      = (which < 256) ? WqT : WoT;
    const int bxx = which & 255;
    const int kt = (bxx & 15) * 64, nt = (bxx >> 4) * 64;
#pragma unroll
    for (int r = 0; r < 4; ++r) {
        int kl = (t >> 4) + 16 * r;
        int n0 = (t & 15) * 4;
        f32x4 f = *(const f32x4*)(W + (size_t)(kt + kl) * 1024 + nt + n0);
#pragma unroll
        for (int j = 0; j < 4; ++j) T[n0 + j][kl] = f2bf(f[j]);
    }
    __syncthreads();
#pragma unroll
    for (int r = 0; r < 2; ++r) {
        int nl = (t >> 3) + 32 * r;
        int k0 = (t & 7) * 8;
        short8_t vv;
#pragma unroll
        for (int j = 0; j < 8; ++j) vv[j] = T[nl][k0 + j];
        *(short8_t*)(Wt + (size_t)(nt + nl) * 1024 + kt + k0) = vv;
    }
}

// ---------------- GEMM 128x128  C[M][N] = A[M][K]*Bt[N][K]^T + bias ----------------
// 2-phase double-buffered staging: issue next K-step's global_load_lds into buf^1 BEFORE
// computing buf; ONE __syncthreads per K-step (after compute) drains the prefetch after it
// overlapped the MFMAs. Barriers/K-step 2->1, HBM latency hidden behind compute.
template <typename OutT>
__global__ __launch_bounds__(256) void gemm_bt_kernel(const short* __restrict__ A,
                                                      const short* __restrict__ Bt,
                                                      const float* __restrict__ bias,
                                                      OutT* __restrict__ C,
                                                      int M, int N, int K,
                                                      int qrows, float qscale) {
    __shared__ __align__(16) short As[2][128 * 32];
    __shared__ __align__(16) short Bs[2][128 * 32];
    const int tid  = threadIdx.x;
    const int lane = tid & 63, wave = tid >> 6;
    const int quad = lane >> 4, l16 = lane & 15;
    const int row0 = blockIdx.x * 128, col0 = blockIdx.y * 128;
    const int wm = (wave >> 1) * 64, wn = (wave & 1) * 64;
    const int srow = lane >> 2;
    const int scol = (lane & 3) * 8;
    f32x4 acc[4][4] = {};
    // prologue: stage k=0 into buf 0
#pragma unroll
    for (int r = 0; r < 2; ++r) {
        int rb = r * 64 + wave * 16;
        g2lds16(A  + (size_t)(row0 + rb + srow) * K + scol, &As[0][rb * 32]);
        g2lds16(Bt + (size_t)(col0 + rb + srow) * K + scol, &Bs[0][rb * 32]);
    }
    __syncthreads();
    int buf = 0;
    for (int k0 = 0; k0 < K; k0 += 32) {
        if (k0 + 32 < K) {   // prefetch next K-step into the other buffer
#pragma unroll
            for (int r = 0; r < 2; ++r) {
                int rb = r * 64 + wave * 16;
                g2lds16(A  + (size_t)(row0 + rb + srow) * K + k0 + 32 + scol, &As[buf ^ 1][rb * 32]);
                g2lds16(Bt + (size_t)(col0 + rb + srow) * K + k0 + 32 + scol, &Bs[buf ^ 1][rb * 32]);
            }
        }
        bf16x8 af[4], bfr[4];
#pragma unroll
        for (int mi = 0; mi < 4; ++mi) af[mi]  = *(const bf16x8*)&As[buf][(wm + mi * 16 + l16) * 32 + quad * 8];
#pragma unroll
        for (int ni = 0; ni < 4; ++ni) bfr[ni] = *(const bf16x8*)&Bs[buf][(wn + ni * 16 + l16) * 32 + quad * 8];
#pragma unroll
        for (int mi = 0; mi < 4; ++mi)
#pragma unroll
            for (int ni = 0; ni < 4; ++ni)
                acc[mi][ni] = __builtin_amdgcn_mfma_f32_16x16x32_bf16(af[mi], bfr[ni], acc[mi][ni], 0, 0, 0);
        __syncthreads();   // drains prefetch vmcnt + fences buf reads vs next overwrite
        buf ^= 1;
    }
#pragma unroll
    for (int mi = 0; mi < 4; ++mi) {
#pragma unroll
        for (int ni = 0; ni < 4; ++ni) {
            int col = col0 + wn + ni * 16 + l16;
            float bv = bias[col];
#pragma unroll
            for (int i = 0; i < 4; ++i) {
                int row = row0 + wm + mi * 16 + quad * 4 + i;
                float val = acc[mi][ni][i] + bv;
                if (row < qrows) val *= qscale;
                if constexpr (sizeof(OutT) == 2) C[(size_t)row * N + col] = (OutT)f2bf(val);
                else                             C[(size_t)row * N + col] = (OutT)val;
            }
        }
    }
}

// ---------------- GEMM 64x128 tiles, same 2-phase structure ----------------
__global__ __launch_bounds__(256) void gemm_bt64_kernel(const short* __restrict__ A,
                                                        const short* __restrict__ Bt,
                                                        const float* __restrict__ bias,
                                                        float* __restrict__ C,
                                                        int M, int N, int K) {
    __shared__ __align__(16) short As[2][64 * 32];
    __shared__ __align__(16) short Bs[2][128 * 32];
    const int tid  = threadIdx.x;
    const int lane = tid & 63, wave = tid >> 6;
    const int quad = lane >> 4, l16 = lane & 15;
    const int row0 = blockIdx.x * 64, col0 = blockIdx.y * 128;
    const int wn = wave * 32;
    const int srow = lane >> 2;
    const int scol = (lane & 3) * 8;
    f32x4 acc[4][2] = {};
    {
        int rb = wave * 16;
        g2lds16(A + (size_t)(row0 + rb + srow) * K + scol, &As[0][rb * 32]);
#pragma unroll
        for (int r = 0; r < 2; ++r) {
            int rb2 = r * 64 + wave * 16;
            g2lds16(Bt + (size_t)(col0 + rb2 + srow) * K + scol, &Bs[0][rb2 * 32]);
        }
    }
    __syncthreads();
    int buf = 0;
    for (int k0 = 0; k0 < K; k0 += 32) {
        if (k0 + 32 < K) {
            int rb = wave * 16;
            g2lds16(A + (size_t)(row0 + rb + srow) * K + k0 + 32 + scol, &As[buf ^ 1][rb * 32]);
#pragma unroll
            for (int r = 0; r < 2; ++r) {
                int rb2 = r * 64 + wave * 16;
                g2lds16(Bt + (size_t)(col0 + rb2 + srow) * K + k0 + 32 + scol, &Bs[buf ^ 1][rb2 * 32]);
            }
        }
        bf16x8 af[4], bfr[2];
#pragma unroll
        for (int mi = 0; mi < 4; ++mi) af[mi]  = *(const bf16x8*)&As[buf][(mi * 16 + l16) * 32 + quad * 8];
#pragma unroll
        for (int ni = 0; ni < 2; ++ni) bfr[ni] = *(const bf16x8*)&Bs[buf][(wn + ni * 16 + l16) * 32 + quad * 8];
#pragma unroll
        for (int mi = 0; mi < 4; ++mi)
#pragma unroll
            for (int ni = 0; ni < 2; ++ni)
                acc[mi][ni] = __builtin_amdgcn_mfma_f32_16x16x32_bf16(af[mi], bfr[ni], acc[mi][ni], 0, 0, 0);
        __syncthreads();
        buf ^= 1;
    }
#pragma unroll
    for (int mi = 0; mi < 4; ++mi) {
#pragma unroll
        for (int ni = 0; ni < 2; ++ni) {
            int col = col0 + wn + ni * 16 + l16;
            float bv = bias[col];
#pragma unroll
            for (int i = 0; i < 4; ++i) {
                int row = row0 + mi * 16 + quad * 4 + i;
                C[(size_t)row * N + col] = acc[mi][ni][i] + bv;
            }
        }
    }
}

// ---------------- P_v [b*2048+s][1024] head slice -> VT[(h*2+b)*64+d][2048] ----------------
__global__ __launch_bounds__(256) void transpose_v_kernel(const short* __restrict__ Pv,
                                                          short* __restrict__ VT) {
    __shared__ short T[64][65];
    const int t = threadIdx.x;
    const int hb = blockIdx.x, st = blockIdx.y * 64;
    const int h = hb >> 1, b = hb & 1;
#pragma unroll
    for (int r = 0; r < 2; ++r) {
        int sl = (t >> 3) + 32 * r;
        short8_t v = *(const short8_t*)(Pv + (size_t)(b * 2048 + st + sl) * 1024 + h * 64 + (t & 7) * 8);
#pragma unroll
        for (int j = 0; j < 8; ++j) T[(t & 7) * 8 + j][sl] = v[j];
    }
    __syncthreads();
#pragma unroll
    for (int r = 0; r < 2; ++r) {
        int dl = (t >> 3) + 32 * r;
        short8_t v;
#pragma unroll
        for (int j = 0; j < 8; ++j) v[j] = T[dl][(t & 7) * 8 + j];
        *(short8_t*)(VT + ((size_t)hb * 64 + dl) * 2048 + st + (t & 7) * 8) = v;
    }
}

// ---------------- flash attention v12 = v9 (proven 52.2us) + s_setprio around MFMA body ----------------
// v10 (miq=4): spilled. v11 (V from L2): latency-exposed scattered reads, MfmaUtil 28->19.
// Both reverted. v9 structure: miq=2, K+V staged in LDS (K permuted), 1 barrier/tile,
// ones-MFMA row sums. T5 setprio(1) wraps the MFMA-dense per-p body (attn +4-7% in m191).
__global__ __launch_bounds__(256, 2) void attn_kernel(const short* __restrict__ P,
                                                      const short* __restrict__ VT,
                                                      short* __restrict__ O) {
    constexpr int LDK = 72;   // 144B rows: b128 frag reads conflict-free
    constexpr int LDV = 136;  // 272B rows: b128 frag reads conflict-free
    constexpr int LDO = 72;   // epilogue transpose stride
    union SmemU {
        struct { short Ks[2][128 * LDK]; short Vs[2][64 * LDV]; } s;
        short OT[128 * LDO];
    };
    __shared__ __align__(16) SmemU sm;

    const int t = threadIdx.x;
    const int lane = t & 63, wave = t >> 6;
    const int quad = lane >> 4, l16 = lane & 15;
    // XCD swizzle: 512 blocks, xcd = bx&7 -> each XCD owns 4 hb (K/V slices fit its L2)
    const int bx = blockIdx.x;
    const int xcd = bx & 7, bi = bx >> 3;
    const int hb = xcd * 4 + (bi & 3), qt = bi >> 2;   // hb 0..31, qt 0..15 (128-row q tiles)
    const int h = hb >> 1, b = hb & 1;
    const short* Pq  = P + (size_t)(b * 2048 + qt * 128) * 1024 + h * 64;
    const short* Pk  = P + (size_t)(4096 + b * 2048) * 1024 + h * 64;
    const short* VTh = VT + (size_t)hb * 64 * 2048;
    const int wq = wave * 32;   // 32 q rows per wave

    // Q fragments: registers for the whole KV loop (B-operand layout = Q rows)
    bf16x8 qf[2][2];
#pragma unroll
    for (int miq = 0; miq < 2; ++miq)
#pragma unroll
        for (int kh = 0; kh < 2; ++kh)
            qf[miq][kh] = *(const bf16x8*)(Pq + (size_t)(wq + miq * 16 + l16) * 1024 + kh * 32 + quad * 8);

    // ones A-operand for the row-sum MFMA
    bf16x8 ones;
#pragma unroll
    for (int j = 0; j < 8; ++j) ones[j] = (__bf16)1.0f;

    f32x4 oacc[4][2] = {};   // [di][miq], O^T C-layout: d=quad*4+i, q=l16
    f32x4 osum[2] = {};      // row-sum accumulator

    // K staging: 32 rows/pass x 4; LDS row permuted within the 32-row group
    const int krow = t >> 3, kc8 = (t & 7) * 8;
    const int kj = krow & 7, kq = krow >> 3;
    const int lrow32 = (kj >= 4 ? 16 + (kj - 4) : kj) + kq * 4;   // permuted row within group
    // V staging: 16 rows/pass x 4 (kv-contiguous, unpermuted)
    const int vrow = t >> 4, vc8 = (t & 15) * 8;

    short8_t kreg[4], vreg[4];
#pragma unroll
    for (int it = 0; it < 4; ++it) {
        kreg[it] = *(const short8_t*)(Pk + (size_t)(it * 32 + krow) * 1024 + kc8);
        vreg[it] = *(const short8_t*)(VTh + (size_t)(it * 16 + vrow) * 2048 + vc8);
    }

    for (int tile = 0; tile < 16; ++tile) {
        const int buf = tile & 1;
        short* Ksb = sm.s.Ks[buf];
        short* Vsb = sm.s.Vs[buf];
#pragma unroll
        for (int it = 0; it < 4; ++it) {
            *(short8_t*)&Ksb[(it * 32 + lrow32) * LDK + kc8] = kreg[it];
            *(short8_t*)&Vsb[(it * 16 + vrow) * LDV + vc8] = vreg[it];
        }
        __syncthreads();
        if (tile + 1 < 16) {   // global prefetch overlaps the whole compute phase
            int kv0 = (tile + 1) * 128;
#pragma unroll
            for (int it = 0; it < 4; ++it) {
                kreg[it] = *(const short8_t*)(Pk + (size_t)(kv0 + it * 32 + krow) * 1024 + kc8);
                vreg[it] = *(const short8_t*)(VTh + (size_t)(it * 16 + vrow) * 2048 + kv0 + vc8);
            }
        }
#pragma unroll
        for (int p = 0; p < 4; ++p) {   // 4 pairs of 16-row chunks = 128 kv
            // K A-frags: chunkA rows p*32+l16, chunkB rows p*32+16+l16 (permuted kv space)
            bf16x8 aA0 = *(const bf16x8*)&Ksb[(p * 32 + l16) * LDK + quad * 8];
            bf16x8 aA1 = *(const bf16x8*)&Ksb[(p * 32 + l16) * LDK + 32 + quad * 8];
            bf16x8 aB0 = *(const bf16x8*)&Ksb[(p * 32 + 16 + l16) * LDK + quad * 8];
            bf16x8 aB1 = *(const bf16x8*)&Ksb[(p * 32 + 16 + l16) * LDK + 32 + quad * 8];
            // V A-frags for K=32 PV: lane d=l16, k(kv)=quad*8+j -> contiguous b128
            bf16x8 vA[4];
#pragma unroll
            for (int di = 0; di < 4; ++di)
                vA[di] = *(const bf16x8*)&Vsb[(di * 16 + l16) * LDV + p * 32 + quad * 8];
            __builtin_amdgcn_s_setprio(1);
#pragma unroll
            for (int miq = 0; miq < 2; ++miq) {
                f32x4 sA = {}, sB = {};
                sA = __builtin_amdgcn_mfma_f32_16x16x32_bf16(aA0, qf[miq][0], sA, 0, 0, 0);
                sB = __builtin_amdgcn_mfma_f32_16x16x32_bf16(aB0, qf[miq][0], sB, 0, 0, 0);
                sA = __builtin_amdgcn_mfma_f32_16x16x32_bf16(aA1, qf[miq][1], sA, 0, 0, 0);
                sB = __builtin_amdgcn_mfma_f32_16x16x32_bf16(aB1, qf[miq][1], sB, 0, 0, 0);
                // exp2 (scale folded into Q); lane's 8 values = kv quad*8+{0..7} of this pair
                float eA0 = __builtin_amdgcn_exp2f(sA[0]);
                float eA1 = __builtin_amdgcn_exp2f(sA[1]);
                float eA2 = __builtin_amdgcn_exp2f(sA[2]);
                float eA3 = __builtin_amdgcn_exp2f(sA[3]);
                float eB0 = __builtin_amdgcn_exp2f(sB[0]);
                float eB1 = __builtin_amdgcn_exp2f(sB[1]);
                float eB2 = __builtin_amdgcn_exp2f(sB[2]);
                float eB3 = __builtin_amdgcn_exp2f(sB[3]);
                union { unsigned u[4]; bf16x8 b8; } pb;
                pb.u[0] = pack_ru(eA0, eA1);
                pb.u[1] = pack_ru(eA2, eA3);
                pb.u[2] = pack_ru(eB0, eB1);
                pb.u[3] = pack_ru(eB2, eB3);
                // row sums via MFMA: D[r][q] = sum_kv pb[kv][q], identical across r
                osum[miq] = __builtin_amdgcn_mfma_f32_16x16x32_bf16(ones, pb.b8, osum[miq], 0, 0, 0);
                // O^T += V^T * P at K=32 (full rate)
#pragma unroll
                for (int di = 0; di < 4; ++di)
                    oacc[di][miq] = __builtin_amdgcn_mfma_f32_16x16x32_bf16(vA[di], pb.b8, oacc[di][miq], 0, 0, 0);
            }
            __builtin_amdgcn_s_setprio(0);
        }
        // no end-of-tile barrier: double-buffered Ks/Vs + top-of-loop barrier make it redundant
    }

    // full row sums came from the ones-MFMA; aligned with O^T cols (q=l16) by construction
    float rinv[2];
#pragma unroll
    for (int miq = 0; miq < 2; ++miq) rinv[miq] = 1.0f / osum[miq][0];

    __syncthreads();   // all Ks/Vs reads done -> OT may alias them

    // O^T -> LDS (bf16), then coalesced row-major store
#pragma unroll
    for (int di = 0; di < 4; ++di) {
#pragma unroll
        for (int miq = 0; miq < 2; ++miq) {
            float v0 = oacc[di][miq][0] * rinv[miq];
            float v1 = oacc[di][miq][1] * rinv[miq];
            float v2 = oacc[di][miq][2] * rinv[miq];
            float v3 = oacc[di][miq][3] * rinv[miq];
            uint2 w;
            w.x = pack_ru(v0, v1);
            w.y = pack_ru(v2, v3);
            int q = wq + miq * 16 + l16;
            *(uint2*)&sm.OT[q * LDO + di * 16 + quad * 4] = w;
        }
    }
    __syncthreads();
    {
        const int orow = t >> 1, ocol = (t & 1) * 32;
        short* dst = O + (size_t)(b * 2048 + qt * 128 + orow) * 1024 + h * 64 + ocol;
#pragma unroll
        for (int c = 0; c < 4; ++c)
            *(short8_t*)(dst + c * 8) = *(const short8_t*)&sm.OT[orow * LDO + ocol + c * 8];
    }
}

extern "C" void kernel_launch(void* const* d_in, const int* in_sizes, int n_in,
                              void* d_out, int out_size, void* d_ws, size_t ws_size,
                              hipStream_t stream) {
    (void)in_sizes; (void)n_in; (void)out_size; (void)ws_size;
    const float* q  = (const float*)d_in[0];
    const float* k  = (const float*)d_in[1];
    const float* v  = (const float*)d_in[2];
    const float* Wq = (const float*)d_in[3];
    const float* bq = (const float*)d_in[4];
    const float* Wo = (const float*)d_in[5];
    const float* bo = (const float*)d_in[6];
    float* out = (float*)d_out;

    short* Xcat = (short*)d_ws;                        // [12288][1024] bf16
    short* WqT  = Xcat + (size_t)12288 * 1024;         // [1024][1024]
    short* WoT  = WqT + (size_t)1024 * 1024;           // [1024][1024]
    short* P    = WoT + (size_t)1024 * 1024;           // [12288][1024] (q|k|v projections)
    short* VT   = P + (size_t)12288 * 1024;            // [32][64][2048]
    short* O    = VT + (size_t)32 * 64 * 2048;         // [4096][1024]

    // softmax scale * log2(e), folded into Q rows of the projection GEMM
    const float qscale = 0.022097086912079608f * 1.4426950408889634f;

    prep_kernel<<<12800, 256, 0, stream>>>(q, k, v, Xcat, Wq, WqT, Wo, WoT);
    gemm_bt_kernel<short><<<dim3(96, 8), 256, 0, stream>>>(Xcat, WqT, bq, P, 12288, 1024, 1024, 4096, qscale);
    transpose_v_kernel<<<dim3(32, 32), 256, 0, stream>>>(P + (size_t)8192 * 1024, VT);
    attn_kernel<<<512, 256, 0, stream>>>(P, VT, O);
    gemm_bt64_kernel<<<dim3(64, 8), 256, 0, stream>>>(O, WoT, bo, out, 4096, 1024, 1024);
}